// Round 1
// baseline (108.743 us; speedup 1.0000x reference)
//
#include <hip/hip_runtime.h>

// Mamba-2 SSD forward: B=2, L=4096, H=16, P=S=64, chunk=64.
// Phase1: per-(b,h,chunk) Y_intra + h_final + decay_chunk
// Scan:   per-(b,h) sequential inter-chunk state recurrence (in-place in ws)
// Phase3: per-(b,h,chunk) Y += decay_from_start * (C @ h_inter)

#define BSZ 2
#define LSEQ 4096
#define NH 16
#define PP 64
#define SS 64
#define CS 64
#define NC (LSEQ / CS)      // 64 chunks
#define CSP (CS + 4)        // padded stride for transposed LDS tiles (16B-aligned rows)
#define SCAN_G 8            // blocks per (b,h) in the scan
#define HWS_ELEMS ((size_t)BSZ * NH * NC * SS * PP)

__global__ __launch_bounds__(256) void ssd_phase1(
    const float* __restrict__ Xg, const float* __restrict__ Ag,
    const float* __restrict__ Bg, const float* __restrict__ Cg,
    float* __restrict__ Yg, float* __restrict__ hws, float* __restrict__ dws)
{
    __shared__ __align__(16) float sX[CS][PP];    // X[c][p]
    __shared__ __align__(16) float sBt[SS][CSP];  // B^T: [s][c]
    __shared__ __align__(16) float sCt[SS][CSP];  // C^T: [s][i]
    __shared__ __align__(16) float sMt[CS][CSP];  // (L*CB)^T: [j][i]
    __shared__ float sA[CS];                      // inclusive cumsum of A
    __shared__ float sDte[CS];                    // exp(Acs[63]-Acs[c])

    const int tid = threadIdx.x;
    const int n = blockIdx.x % NC;
    const int h = (blockIdx.x / NC) % NH;
    const int b = blockIdx.x / (NC * NH);
    const int row0 = b * LSEQ + n * CS;

    // ---- inclusive cumsum of A over the chunk ----
    if (tid < CS) sA[tid] = Ag[(size_t)(row0 + tid) * NH + h];
    __syncthreads();
    for (int off = 1; off < CS; off <<= 1) {
        float v = 0.f;
        if (tid < CS && tid >= off) v = sA[tid - off];
        __syncthreads();
        if (tid < CS) sA[tid] += v;
        __syncthreads();
    }
    const float aN = sA[CS - 1];
    if (tid < CS) sDte[tid] = __expf(aN - sA[tid]);  // consumed after next barrier

    // ---- stage tiles (X row-major, B/C transposed). X stride == B/C stride == 64. ----
    {
        const int c  = tid >> 4;
        const int s0 = (tid & 15) << 2;
        #pragma unroll
        for (int cc = 0; cc < 4; ++cc) {
            const int cr = c + cc * 16;
            const size_t gofs = ((size_t)(row0 + cr) * NH + h) * PP + s0;
            const float4 xv = *(const float4*)&Xg[gofs];
            *(float4*)&sX[cr][s0] = xv;
            const float4 bv = *(const float4*)&Bg[gofs];
            sBt[s0 + 0][cr] = bv.x; sBt[s0 + 1][cr] = bv.y;
            sBt[s0 + 2][cr] = bv.z; sBt[s0 + 3][cr] = bv.w;
            const float4 cv = *(const float4*)&Cg[gofs];
            sCt[s0 + 0][cr] = cv.x; sCt[s0 + 1][cr] = cv.y;
            sCt[s0 + 2][cr] = cv.z; sCt[s0 + 3][cr] = cv.w;
        }
    }
    __syncthreads();

    const int r0 = (tid >> 4) << 2;   // row-tile base (i or s), 0..60
    const int q0 = (tid & 15) << 2;   // col-tile base (j or p), 0..60

    // ---- M = L ∘ (C @ B^T), stored transposed ----
    {
        float cb[4][4] = {};
        #pragma unroll 8
        for (int s = 0; s < SS; ++s) {
            const float4 cv = *(const float4*)&sCt[s][r0];
            const float4 bv = *(const float4*)&sBt[s][q0];
            const float ca[4] = {cv.x, cv.y, cv.z, cv.w};
            const float ba[4] = {bv.x, bv.y, bv.z, bv.w};
            #pragma unroll
            for (int ii = 0; ii < 4; ++ii)
                #pragma unroll
                for (int jj = 0; jj < 4; ++jj)
                    cb[ii][jj] += ca[ii] * ba[jj];
        }
        #pragma unroll
        for (int ii = 0; ii < 4; ++ii) {
            const int i = r0 + ii;
            const float ai = sA[i];
            #pragma unroll
            for (int jj = 0; jj < 4; ++jj) {
                const int j = q0 + jj;
                // masked entries: ref gives exp(-100)≈3.7e-44 -> 0 is well within tol
                sMt[j][i] = (i >= j) ? __expf(ai - sA[j]) * cb[ii][jj] : 0.f;
            }
        }
    }
    __syncthreads();

    // ---- Y_intra = M @ X ----
    {
        float acc[4][4] = {};
        #pragma unroll 8
        for (int j = 0; j < CS; ++j) {
            const float4 mv = *(const float4*)&sMt[j][r0];
            const float4 xv = *(const float4*)&sX[j][q0];
            const float ma[4] = {mv.x, mv.y, mv.z, mv.w};
            const float xa[4] = {xv.x, xv.y, xv.z, xv.w};
            #pragma unroll
            for (int ii = 0; ii < 4; ++ii)
                #pragma unroll
                for (int pp = 0; pp < 4; ++pp)
                    acc[ii][pp] += ma[ii] * xa[pp];
        }
        #pragma unroll
        for (int ii = 0; ii < 4; ++ii) {
            const int i = r0 + ii;
            float4 o; o.x = acc[ii][0]; o.y = acc[ii][1]; o.z = acc[ii][2]; o.w = acc[ii][3];
            *(float4*)&Yg[((size_t)(row0 + i) * NH + h) * PP + q0] = o;
        }
    }

    // ---- h_final[s][p] = sum_c dte[c] * B[c][s] * X[c][p] ----
    {
        float acc[4][4] = {};
        #pragma unroll 8
        for (int c = 0; c < CS; ++c) {
            const float dte = sDte[c];
            const float4 xv = *(const float4*)&sX[c][q0];
            const float xs[4] = {dte * xv.x, dte * xv.y, dte * xv.z, dte * xv.w};
            const float bb[4] = {sBt[r0 + 0][c], sBt[r0 + 1][c],
                                 sBt[r0 + 2][c], sBt[r0 + 3][c]};
            #pragma unroll
            for (int k = 0; k < 4; ++k)
                #pragma unroll
                for (int pp = 0; pp < 4; ++pp)
                    acc[k][pp] += bb[k] * xs[pp];
        }
        const size_t hbase = ((size_t)((b * NH + h) * NC + n)) * (SS * PP);
        #pragma unroll
        for (int k = 0; k < 4; ++k) {
            float4 o; o.x = acc[k][0]; o.y = acc[k][1]; o.z = acc[k][2]; o.w = acc[k][3];
            *(float4*)&hws[hbase + (size_t)(r0 + k) * PP + q0] = o;
        }
    }

    if (tid == 0) dws[(b * NH + h) * NC + n] = __expf(aN);
}

// in-place: h_final[c] -> h_inter[c] (state BEFORE chunk c)
__global__ __launch_bounds__(256) void ssd_scan(float* __restrict__ hws,
                                                const float* __restrict__ dws)
{
    __shared__ float sD[NC];
    const int tid = threadIdx.x;
    const int bh = blockIdx.x / SCAN_G;
    const int g  = blockIdx.x % SCAN_G;
    if (tid < NC) sD[tid] = dws[bh * NC + tid];
    __syncthreads();

    float* base = hws + (size_t)bh * NC * (SS * PP) + g * (SS * PP / SCAN_G) + tid * 2;
    float cx = 0.f, cy = 0.f;
    for (int c = 0; c < NC; ++c) {
        const float d = sD[c];
        float2* p = (float2*)(base + (size_t)c * (SS * PP));
        const float2 hf = *p;
        float2 old; old.x = cx; old.y = cy;
        *p = old;
        cx = d * cx + hf.x;
        cy = d * cy + hf.y;
    }
}

__global__ __launch_bounds__(256) void ssd_phase3(
    const float* __restrict__ Ag, const float* __restrict__ Cg,
    const float* __restrict__ hws, float* __restrict__ Yg)
{
    __shared__ __align__(16) float sCt[SS][CSP];  // C^T: [s][i]
    __shared__ __align__(16) float sH[SS][PP];    // h_inter[s][p]
    __shared__ float sA[CS];

    const int tid = threadIdx.x;
    const int n = blockIdx.x % NC;
    const int h = (blockIdx.x / NC) % NH;
    const int b = blockIdx.x / (NC * NH);
    const int row0 = b * LSEQ + n * CS;

    if (tid < CS) sA[tid] = Ag[(size_t)(row0 + tid) * NH + h];
    __syncthreads();
    for (int off = 1; off < CS; off <<= 1) {
        float v = 0.f;
        if (tid < CS && tid >= off) v = sA[tid - off];
        __syncthreads();
        if (tid < CS) sA[tid] += v;
        __syncthreads();
    }

    {
        const int c  = tid >> 4;
        const int s0 = (tid & 15) << 2;
        const size_t hbase = ((size_t)((b * NH + h) * NC + n)) * (SS * PP);
        #pragma unroll
        for (int cc = 0; cc < 4; ++cc) {
            const int cr = c + cc * 16;
            const float4 cv = *(const float4*)&Cg[((size_t)(row0 + cr) * NH + h) * SS + s0];
            sCt[s0 + 0][cr] = cv.x; sCt[s0 + 1][cr] = cv.y;
            sCt[s0 + 2][cr] = cv.z; sCt[s0 + 3][cr] = cv.w;
            const float4 hv = *(const float4*)&hws[hbase + (size_t)cr * PP + s0];
            *(float4*)&sH[cr][s0] = hv;
        }
    }
    __syncthreads();

    const int r0 = (tid >> 4) << 2;
    const int q0 = (tid & 15) << 2;

    float acc[4][4] = {};
    #pragma unroll 8
    for (int s = 0; s < SS; ++s) {
        const float4 cv = *(const float4*)&sCt[s][r0];
        const float4 hv = *(const float4*)&sH[s][q0];
        const float ca[4] = {cv.x, cv.y, cv.z, cv.w};
        const float ha[4] = {hv.x, hv.y, hv.z, hv.w};
        #pragma unroll
        for (int ii = 0; ii < 4; ++ii)
            #pragma unroll
            for (int pp = 0; pp < 4; ++pp)
                acc[ii][pp] += ca[ii] * ha[pp];
    }
    #pragma unroll
    for (int ii = 0; ii < 4; ++ii) {
        const int i = r0 + ii;
        const float dfs = __expf(sA[i]);
        float4* yp = (float4*)&Yg[((size_t)(row0 + i) * NH + h) * PP + q0];
        float4 y = *yp;
        y.x += dfs * acc[ii][0];
        y.y += dfs * acc[ii][1];
        y.z += dfs * acc[ii][2];
        y.w += dfs * acc[ii][3];
        *yp = y;
    }
}

extern "C" void kernel_launch(void* const* d_in, const int* in_sizes, int n_in,
                              void* d_out, int out_size, void* d_ws, size_t ws_size,
                              hipStream_t stream) {
    const float* X  = (const float*)d_in[0];
    const float* A  = (const float*)d_in[1];
    const float* Bm = (const float*)d_in[2];
    const float* Cm = (const float*)d_in[3];
    // d_in[4] = chunk_size (=64, hardcoded)
    float* Y   = (float*)d_out;
    float* hws = (float*)d_ws;                 // [BSZ*NH*NC][SS][PP] = 33.55 MB
    float* dws = hws + HWS_ELEMS;              // [BSZ*NH*NC] chunk decays

    ssd_phase1<<<BSZ * NH * NC, 256, 0, stream>>>(X, A, Bm, Cm, Y, hws, dws);
    ssd_scan  <<<BSZ * NH * SCAN_G, 256, 0, stream>>>(hws, dws);
    ssd_phase3<<<BSZ * NH * NC, 256, 0, stream>>>(A, Cm, hws, Y);
}

// Round 2
// 68.981 us; speedup vs baseline: 1.5764x; 1.5764x over previous
//
#include <hip/hip_runtime.h>

// Mamba-2 SSD forward, MFMA bf16 version. B=2, L=4096, H=16, P=S=64, chunk=64.
// phase1: per-(b,h,chunk): CB=C·B^T -> M=L∘CB -> Y_intra=M·X ; h_final=(dte∘B)^T·X
// scan:   per-(b,h) sequential inter-chunk state recurrence (in-place, fp32)
// phase3: per-(b,h,chunk): Y += exp(Acs)∘(C·h_inter)

#define BSZ 2
#define LSEQ 4096
#define NH 16
#define PP 64
#define SS 64
#define CS 64
#define NC (LSEQ / CS)
#define SCAN_G 8
#define HWS_ELEMS ((size_t)BSZ * NH * NC * SS * PP)

typedef float f32x4 __attribute__((ext_vector_type(4)));
typedef __bf16 bf16x8 __attribute__((ext_vector_type(8)));

union FragU { uint4 u; bf16x8 b; };

__device__ __forceinline__ unsigned short f2b(float x) {
    union { float f; unsigned u; } c; c.f = x;
    unsigned r = c.u + 0x7fffu + ((c.u >> 16) & 1u);   // RNE bf16
    return (unsigned short)(r >> 16);
}

// element-index (ushort) swizzled addressing, 64 elems per row.
// XOR swizzles bits 3..5 of the column -> 16B-aligned vector reads stay aligned.
__device__ __forceinline__ int rm_e(int row, int k) { return row * 64 + (k ^ ((row & 7) << 3)); }
__device__ __forceinline__ int tr_e(int row, int k) { return row * 64 + (k ^ (((row >> 1) & 7) << 3)); }

__device__ __forceinline__ bf16x8 frag_rm(const unsigned short* buf, int tile, int kk, int l) {
    const int row = tile * 16 + (l & 15);
    const int k = kk * 32 + ((l >> 4) << 3);
    FragU f; f.u = *(const uint4*)&buf[rm_e(row, k)];
    return f.b;
}
__device__ __forceinline__ bf16x8 frag_tr(const unsigned short* buf, int tile, int kk, int l) {
    const int row = tile * 16 + (l & 15);
    const int k = kk * 32 + ((l >> 4) << 3);
    FragU f; f.u = *(const uint4*)&buf[tr_e(row, k)];
    return f.b;
}

__global__ __launch_bounds__(256) void ssd_phase1(
    const float* __restrict__ Xg, const float* __restrict__ Ag,
    const float* __restrict__ Bg, const float* __restrict__ Cg,
    float* __restrict__ Yg, float* __restrict__ hws, float* __restrict__ dws)
{
    __shared__ __align__(16) unsigned short sB[64 * 64];   // B row-major [c][s]
    __shared__ __align__(16) unsigned short sCM[64 * 64];  // C row-major, then M row-major [i][j]
    __shared__ __align__(16) unsigned short sXt[64 * 64];  // X^T [p][c]
    __shared__ __align__(16) unsigned short sBt[64 * 64];  // B^T [s][c]
    __shared__ float sE[64], sR[64], sDte[64];

    const int tid = threadIdx.x;
    const int l = tid & 63;
    const int w = tid >> 6;
    const int n = blockIdx.x % NC;
    const int h = (blockIdx.x / NC) % NH;
    const int b = blockIdx.x / (NC * NH);
    const int row0 = b * LSEQ + n * CS;

    // wave0: cumsum of A via shfl scan; factorized decays
    if (tid < 64) {
        float a = Ag[(size_t)(row0 + tid) * NH + h];
        #pragma unroll
        for (int off = 1; off < 64; off <<= 1) {
            float v = __shfl_up(a, off, 64);
            if (tid >= off) a += v;
        }
        sE[tid] = __expf(a);
        sR[tid] = __expf(-a);
        const float a63 = __shfl(a, 63, 64);
        sDte[tid] = __expf(a63 - a);
        if (tid == 63) dws[(b * NH + h) * NC + n] = __expf(a);
    }

    // stage: fp32 global -> bf16 LDS (row-major B,C; transposed X,B)
    #pragma unroll
    for (int it = 0; it < 4; ++it) {
        const int c = (tid >> 4) + it * 16;
        const int p0 = (tid & 15) * 4;
        const size_t g = ((size_t)(row0 + c) * NH + h) * 64 + p0;
        const float4 xv = *(const float4*)&Xg[g];
        const float4 bv = *(const float4*)&Bg[g];
        const float4 cv = *(const float4*)&Cg[g];
        ushort4 bw; bw.x = f2b(bv.x); bw.y = f2b(bv.y); bw.z = f2b(bv.z); bw.w = f2b(bv.w);
        ushort4 cw; cw.x = f2b(cv.x); cw.y = f2b(cv.y); cw.z = f2b(cv.z); cw.w = f2b(cv.w);
        *(ushort4*)&sB[rm_e(c, p0)] = bw;
        *(ushort4*)&sCM[rm_e(c, p0)] = cw;
        sXt[tr_e(p0 + 0, c)] = f2b(xv.x);
        sXt[tr_e(p0 + 1, c)] = f2b(xv.y);
        sXt[tr_e(p0 + 2, c)] = f2b(xv.z);
        sXt[tr_e(p0 + 3, c)] = f2b(xv.w);
        sBt[tr_e(p0 + 0, c)] = bw.x;
        sBt[tr_e(p0 + 1, c)] = bw.y;
        sBt[tr_e(p0 + 2, c)] = bw.z;
        sBt[tr_e(p0 + 3, c)] = bw.w;
    }
    __syncthreads();

    const f32x4 zero = {0.f, 0.f, 0.f, 0.f};
    const int il = (l >> 4) << 2;  // D-frag local row base

    // ---- mm1: CB = C·B^T (wave w owns rows 16w..16w+15) ----
    f32x4 accCB[4] = {zero, zero, zero, zero};
    #pragma unroll
    for (int kk = 0; kk < 2; ++kk) {
        const bf16x8 aC = frag_rm(sCM, w, kk, l);
        #pragma unroll
        for (int tj = 0; tj < 4; ++tj) {
            const bf16x8 bB = frag_rm(sB, tj, kk, l);
            accCB[tj] = __builtin_amdgcn_mfma_f32_16x16x32_bf16(aC, bB, accCB[tj], 0, 0, 0);
        }
    }
    // M = L∘CB written into sCM (each wave touches only its own 16-row slab ->
    // in-wave mem dependency, no barrier needed)
    #pragma unroll
    for (int tj = 0; tj < 4; ++tj) {
        #pragma unroll
        for (int r = 0; r < 4; ++r) {
            const int i = w * 16 + il + r;
            const int j = tj * 16 + (l & 15);
            const float v = (i >= j) ? sE[i] * sR[j] * accCB[tj][r] : 0.f;
            sCM[i * 64 + (j ^ ((i & 7) << 3))] = f2b(v);
        }
    }

    // ---- mm2: Y_intra = M·X  and  mm3: h_final = (dte∘B)^T·X (shared X frags) ----
    f32x4 accY[4] = {zero, zero, zero, zero};
    f32x4 accH[4] = {zero, zero, zero, zero};
    #pragma unroll
    for (int kk = 0; kk < 2; ++kk) {
        const bf16x8 aM = frag_rm(sCM, w, kk, l);
        const bf16x8 aB = frag_tr(sBt, w, kk, l);
        const int c0 = kk * 32 + ((l >> 4) << 3);
        bf16x8 aBs;
        #pragma unroll
        for (int e = 0; e < 8; ++e) aBs[e] = (__bf16)((float)aB[e] * sDte[c0 + e]);
        #pragma unroll
        for (int tp = 0; tp < 4; ++tp) {
            const bf16x8 bX = frag_tr(sXt, tp, kk, l);
            accY[tp] = __builtin_amdgcn_mfma_f32_16x16x32_bf16(aM, bX, accY[tp], 0, 0, 0);
            accH[tp] = __builtin_amdgcn_mfma_f32_16x16x32_bf16(aBs, bX, accH[tp], 0, 0, 0);
        }
    }

    const size_t hb = ((size_t)(b * NH + h) * NC + n) * (size_t)(SS * PP);
    #pragma unroll
    for (int tp = 0; tp < 4; ++tp) {
        #pragma unroll
        for (int r = 0; r < 4; ++r) {
            const int i = w * 16 + il + r;          // row (Y) / s (h_final)
            const int p = tp * 16 + (l & 15);
            Yg[((size_t)(row0 + i) * NH + h) * 64 + p] = accY[tp][r];
            hws[hb + (size_t)i * 64 + p] = accH[tp][r];
        }
    }
}

// in-place: h_final[c] -> h_inter[c] (state BEFORE chunk c)
__global__ __launch_bounds__(256) void ssd_scan(float* __restrict__ hws,
                                                const float* __restrict__ dws)
{
    __shared__ float sD[NC];
    const int tid = threadIdx.x;
    const int bh = blockIdx.x / SCAN_G;
    const int g = blockIdx.x % SCAN_G;
    if (tid < NC) sD[tid] = dws[bh * NC + tid];
    __syncthreads();

    float* base = hws + (size_t)bh * NC * (SS * PP) + g * (SS * PP / SCAN_G) + tid * 2;
    float cx = 0.f, cy = 0.f;
    for (int c = 0; c < NC; ++c) {
        const float d = sD[c];
        float2* p = (float2*)(base + (size_t)c * (SS * PP));
        const float2 hf = *p;
        float2 old; old.x = cx; old.y = cy;
        *p = old;
        cx = d * cx + hf.x;
        cy = d * cy + hf.y;
    }
}

__global__ __launch_bounds__(256) void ssd_phase3(
    const float* __restrict__ Ag, const float* __restrict__ Cg,
    const float* __restrict__ hws, float* __restrict__ Yg)
{
    __shared__ __align__(16) unsigned short sC[64 * 64];   // C row-major [i][s]
    __shared__ __align__(16) unsigned short sHt[64 * 64];  // h^T [p][s]
    __shared__ float sE[64];

    const int tid = threadIdx.x;
    const int l = tid & 63;
    const int w = tid >> 6;
    const int n = blockIdx.x % NC;
    const int h = (blockIdx.x / NC) % NH;
    const int b = blockIdx.x / (NC * NH);
    const int row0 = b * LSEQ + n * CS;
    const size_t hb = ((size_t)(b * NH + h) * NC + n) * (size_t)(SS * PP);

    if (tid < 64) {
        float a = Ag[(size_t)(row0 + tid) * NH + h];
        #pragma unroll
        for (int off = 1; off < 64; off <<= 1) {
            float v = __shfl_up(a, off, 64);
            if (tid >= off) a += v;
        }
        sE[tid] = __expf(a);   // decay_from_start
    }

    #pragma unroll
    for (int it = 0; it < 4; ++it) {
        const int rr = (tid >> 4) + it * 16;    // C row / h s-row
        const int p0 = (tid & 15) * 4;
        const float4 cv = *(const float4*)&Cg[((size_t)(row0 + rr) * NH + h) * 64 + p0];
        ushort4 cw; cw.x = f2b(cv.x); cw.y = f2b(cv.y); cw.z = f2b(cv.z); cw.w = f2b(cv.w);
        *(ushort4*)&sC[rm_e(rr, p0)] = cw;
        const float4 hv = *(const float4*)&hws[hb + (size_t)rr * 64 + p0];
        sHt[tr_e(p0 + 0, rr)] = f2b(hv.x);
        sHt[tr_e(p0 + 1, rr)] = f2b(hv.y);
        sHt[tr_e(p0 + 2, rr)] = f2b(hv.z);
        sHt[tr_e(p0 + 3, rr)] = f2b(hv.w);
    }
    __syncthreads();

    const f32x4 zero = {0.f, 0.f, 0.f, 0.f};
    f32x4 acc[4] = {zero, zero, zero, zero};
    #pragma unroll
    for (int kk = 0; kk < 2; ++kk) {
        const bf16x8 aC = frag_rm(sC, w, kk, l);
        #pragma unroll
        for (int tp = 0; tp < 4; ++tp) {
            const bf16x8 bH = frag_tr(sHt, tp, kk, l);
            acc[tp] = __builtin_amdgcn_mfma_f32_16x16x32_bf16(aC, bH, acc[tp], 0, 0, 0);
        }
    }

    const int il = (l >> 4) << 2;
    #pragma unroll
    for (int tp = 0; tp < 4; ++tp) {
        #pragma unroll
        for (int r = 0; r < 4; ++r) {
            const int i = w * 16 + il + r;
            const int p = tp * 16 + (l & 15);
            const size_t yo = ((size_t)(row0 + i) * NH + h) * 64 + p;
            Yg[yo] += sE[i] * acc[tp][r];
        }
    }
}

extern "C" void kernel_launch(void* const* d_in, const int* in_sizes, int n_in,
                              void* d_out, int out_size, void* d_ws, size_t ws_size,
                              hipStream_t stream) {
    const float* X = (const float*)d_in[0];
    const float* A = (const float*)d_in[1];
    const float* Bm = (const float*)d_in[2];
    const float* Cm = (const float*)d_in[3];
    float* Y = (float*)d_out;
    float* hws = (float*)d_ws;
    float* dws = hws + HWS_ELEMS;

    ssd_phase1<<<BSZ * NH * NC, 256, 0, stream>>>(X, A, Bm, Cm, Y, hws, dws);
    ssd_scan<<<BSZ * NH * SCAN_G, 256, 0, stream>>>(hws, dws);
    ssd_phase3<<<BSZ * NH * NC, 256, 0, stream>>>(A, Cm, hws, Y);
}

// Round 3
// 57.330 us; speedup vs baseline: 1.8968x; 1.2032x over previous
//
#include <hip/hip_runtime.h>

// Mamba-2 SSD forward. B=2, L=4096, H=16, P=S=64, chunk=64, n=64 chunks.
// K1 (ssd_hfinal): h_final^[p][s] (bf16) = sum_c B[c][s] * (dte[c]*X[c][p]); per-chunk decay
// K2 (ssd_scan):   in-place inter-chunk recurrence on bf16 h (fp32 carry)
// K3 (ssd_y):      Y = M.X + dfs*(C.h_inter), written once, fp32

#define BSZ 2
#define LSEQ 4096
#define NH 16
#define NC 64
#define SCAN_G 8
#define HWS_ELEMS ((size_t)BSZ * NH * NC * 64 * 64)   // ushort count

typedef float f32x4 __attribute__((ext_vector_type(4)));
typedef __bf16 bf16x8 __attribute__((ext_vector_type(8)));

union FragU { uint4 u; bf16x8 b; };

__device__ __forceinline__ unsigned short f2b(float x) {
    union { float f; unsigned u; } c; c.f = x;
    unsigned r = c.u + 0x7fffu + ((c.u >> 16) & 1u);   // RNE bf16
    return (unsigned short)(r >> 16);
}
__device__ __forceinline__ float b2f(unsigned short v) {
    union { unsigned u; float f; } c; c.u = ((unsigned)v) << 16;
    return c.f;
}

// element-index swizzles, 64 ushort per row; XOR on col bits 3..5 keeps 16B vectors aligned
__device__ __forceinline__ int rm_e(int row, int k) { return row * 64 + (k ^ ((row & 7) << 3)); }
__device__ __forceinline__ int tr_e(int row, int k) { return row * 64 + (k ^ (((row >> 1) & 7) << 3)); }

// A/B-operand fragment reads. Frag semantics (mfma_f32_16x16x32_bf16):
//   A-op: lane l supplies A[row=l&15][k=(l>>4)*8+e]; B-op: lane l supplies B[k][col=l&15].
//   Both want 8 K-contiguous elems -> storage [rowcol][k] row-major.
__device__ __forceinline__ bf16x8 frag_rm(const unsigned short* buf, int tile, int kk, int l) {
    FragU f; f.u = *(const uint4*)&buf[rm_e(tile * 16 + (l & 15), kk * 32 + ((l >> 4) << 3))];
    return f.b;
}
__device__ __forceinline__ bf16x8 frag_tr(const unsigned short* buf, int tile, int kk, int l) {
    FragU f; f.u = *(const uint4*)&buf[tr_e(tile * 16 + (l & 15), kk * 32 + ((l >> 4) << 3))];
    return f.b;
}

// ---------------- K1: h_final ----------------
__global__ __launch_bounds__(256) void ssd_hfinal(
    const float* __restrict__ Xg, const float* __restrict__ Ag,
    const float* __restrict__ Bg, unsigned short* __restrict__ hws,
    float* __restrict__ dws)
{
    __shared__ __align__(16) unsigned short sBt[64 * 64];  // B^T [s][c]
    __shared__ __align__(16) unsigned short sXt[64 * 64];  // (dte*X)^T [p][c]
    __shared__ float sDte[64];

    const int tid = threadIdx.x;
    const int l = tid & 63;
    const int w = tid >> 6;
    const int n = blockIdx.x & (NC - 1);
    const int h = (blockIdx.x >> 6) & (NH - 1);
    const int b = blockIdx.x >> 10;
    const int row0 = b * LSEQ + n * 64;

    // preload X,B into regs (overlaps wave0's scan)
    float4 xv[4], bv[4];
    const int p0 = (tid & 15) * 4;
    #pragma unroll
    for (int it = 0; it < 4; ++it) {
        const int c = (tid >> 4) + it * 16;
        const unsigned g = ((unsigned)(row0 + c) * NH + h) * 64 + p0;
        xv[it] = *(const float4*)&Xg[g];
        bv[it] = *(const float4*)&Bg[g];
    }
    if (tid < 64) {
        float a = Ag[(unsigned)(row0 + tid) * NH + h];
        #pragma unroll
        for (int off = 1; off < 64; off <<= 1) {
            float v = __shfl_up(a, off, 64);
            if (tid >= off) a += v;
        }
        const float a63 = __shfl(a, 63, 64);
        sDte[tid] = __expf(a63 - a);
        if (tid == 63) dws[(b * NH + h) * NC + n] = __expf(a63);
    }
    __syncthreads();

    #pragma unroll
    for (int it = 0; it < 4; ++it) {
        const int c = (tid >> 4) + it * 16;
        const float dte = sDte[c];
        sBt[tr_e(p0 + 0, c)] = f2b(bv[it].x);
        sBt[tr_e(p0 + 1, c)] = f2b(bv[it].y);
        sBt[tr_e(p0 + 2, c)] = f2b(bv[it].z);
        sBt[tr_e(p0 + 3, c)] = f2b(bv[it].w);
        sXt[tr_e(p0 + 0, c)] = f2b(xv[it].x * dte);
        sXt[tr_e(p0 + 1, c)] = f2b(xv[it].y * dte);
        sXt[tr_e(p0 + 2, c)] = f2b(xv[it].z * dte);
        sXt[tr_e(p0 + 3, c)] = f2b(xv[it].w * dte);
    }
    __syncthreads();

    // h[s][p] = sum_c B^T[s][c] * Xs^T[p][c]; wave w owns s in [16w,16w+16)
    const f32x4 zero = {0.f, 0.f, 0.f, 0.f};
    f32x4 acc[4] = {zero, zero, zero, zero};
    #pragma unroll
    for (int kk = 0; kk < 2; ++kk) {
        const bf16x8 aB = frag_tr(sBt, w, kk, l);
        #pragma unroll
        for (int tp = 0; tp < 4; ++tp)
            acc[tp] = __builtin_amdgcn_mfma_f32_16x16x32_bf16(aB, frag_tr(sXt, tp, kk, l), acc[tp], 0, 0, 0);
    }

    // store hws layout [bh,n][p][s] bf16; lane: s = 16w + (l>>4)*4 + r (consecutive), p = tp*16 + (l&15)
    const unsigned hb = ((unsigned)((b * NH + h) * NC + n)) * 4096u;
    const int sbase = w * 16 + ((l >> 4) << 2);
    #pragma unroll
    for (int tp = 0; tp < 4; ++tp) {
        const int p = tp * 16 + (l & 15);
        ushort4 o;
        o.x = f2b(acc[tp][0]); o.y = f2b(acc[tp][1]);
        o.z = f2b(acc[tp][2]); o.w = f2b(acc[tp][3]);
        *(ushort4*)&hws[hb + (unsigned)p * 64 + sbase] = o;
    }
}

// ---------------- K2: scan (in-place, bf16 storage, fp32 carry) ----------------
__global__ __launch_bounds__(256) void ssd_scan(unsigned short* __restrict__ hws,
                                                const float* __restrict__ dws)
{
    __shared__ float sD[NC];
    const int tid = threadIdx.x;
    const int bh = blockIdx.x / SCAN_G;
    const int g = blockIdx.x % SCAN_G;
    if (tid < NC) sD[tid] = dws[bh * NC + tid];
    __syncthreads();

    unsigned* hw32 = (unsigned*)hws;
    const unsigned base = (unsigned)bh * NC * 2048u + g * 256u + tid;  // uint index, 2 bf16 each
    float cx = 0.f, cy = 0.f;
    unsigned cur = hw32[base];
    #pragma unroll 4
    for (int c = 0; c < NC; ++c) {
        unsigned nxt = 0;
        if (c < NC - 1) nxt = hw32[base + (c + 1) * 2048u];
        const float hx = b2f((unsigned short)(cur & 0xffffu));
        const float hy = b2f((unsigned short)(cur >> 16));
        hw32[base + c * 2048u] = (unsigned)f2b(cx) | ((unsigned)f2b(cy) << 16);
        const float d = sD[c];
        cx = d * cx + hx;
        cy = d * cy + hy;
        cur = nxt;
    }
}

// ---------------- K3: Y = M.X + dfs*(C.h_inter) ----------------
__global__ __launch_bounds__(256) void ssd_y(
    const float* __restrict__ Xg, const float* __restrict__ Ag,
    const float* __restrict__ Bg, const float* __restrict__ Cg,
    const unsigned short* __restrict__ hws, float* __restrict__ Yg)
{
    __shared__ __align__(16) unsigned short sBM[64 * 64];  // B rm [j][s], then M rm [i][j]
    __shared__ __align__(16) unsigned short sC[64 * 64];   // C rm [i][s]
    __shared__ __align__(16) unsigned short sXt[64 * 64];  // X^T [p][j]
    __shared__ __align__(16) unsigned short sH[64 * 64];   // h_inter^T rm [p][s]
    __shared__ float sE[64], sR[64];

    const int tid = threadIdx.x;
    const int l = tid & 63;
    const int w = tid >> 6;
    const int n = blockIdx.x & (NC - 1);
    const int h = (blockIdx.x >> 6) & (NH - 1);
    const int b = blockIdx.x >> 10;
    const int row0 = b * LSEQ + n * 64;
    const unsigned hb = ((unsigned)((b * NH + h) * NC + n)) * 4096u;

    if (tid < 64) {
        float a = Ag[(unsigned)(row0 + tid) * NH + h];
        #pragma unroll
        for (int off = 1; off < 64; off <<= 1) {
            float v = __shfl_up(a, off, 64);
            if (tid >= off) a += v;
        }
        sE[tid] = __expf(a);
        sR[tid] = __expf(-a);
    }
    // stage X,B,C (fp32->bf16, B/C row-major, X transposed)
    {
        const int p0 = (tid & 15) * 4;
        #pragma unroll
        for (int it = 0; it < 4; ++it) {
            const int c = (tid >> 4) + it * 16;
            const unsigned g = ((unsigned)(row0 + c) * NH + h) * 64 + p0;
            const float4 xv = *(const float4*)&Xg[g];
            const float4 bv = *(const float4*)&Bg[g];
            const float4 cv = *(const float4*)&Cg[g];
            ushort4 bw; bw.x = f2b(bv.x); bw.y = f2b(bv.y); bw.z = f2b(bv.z); bw.w = f2b(bv.w);
            ushort4 cw; cw.x = f2b(cv.x); cw.y = f2b(cv.y); cw.z = f2b(cv.z); cw.w = f2b(cv.w);
            *(ushort4*)&sBM[rm_e(c, p0)] = bw;
            *(ushort4*)&sC[rm_e(c, p0)] = cw;
            sXt[tr_e(p0 + 0, c)] = f2b(xv.x);
            sXt[tr_e(p0 + 1, c)] = f2b(xv.y);
            sXt[tr_e(p0 + 2, c)] = f2b(xv.z);
            sXt[tr_e(p0 + 3, c)] = f2b(xv.w);
        }
    }
    // stage h_inter (bf16 raw copy into rm-swizzled layout): thread t -> row t>>2, 16 cols
    {
        const int pr = tid >> 2;
        const int s0 = (tid & 3) * 16;
        const uint4 h0 = *(const uint4*)&hws[hb + (unsigned)pr * 64 + s0];
        const uint4 h1 = *(const uint4*)&hws[hb + (unsigned)pr * 64 + s0 + 8];
        *(uint4*)&sH[rm_e(pr, s0)] = h0;
        *(uint4*)&sH[rm_e(pr, s0 + 8)] = h1;
    }
    __syncthreads();

    const f32x4 zero = {0.f, 0.f, 0.f, 0.f};
    const int il = (l >> 4) << 2;

    // mm1: CB[i][j] = sum_s C[i][s]B[j][s]; wave w owns i in [16w,16w+16)
    f32x4 accCB[4] = {zero, zero, zero, zero};
    #pragma unroll
    for (int kk = 0; kk < 2; ++kk) {
        const bf16x8 aC = frag_rm(sC, w, kk, l);
        #pragma unroll
        for (int tj = 0; tj < 4; ++tj)
            accCB[tj] = __builtin_amdgcn_mfma_f32_16x16x32_bf16(aC, frag_rm(sBM, tj, kk, l), accCB[tj], 0, 0, 0);
    }
    __syncthreads();   // all waves done reading sBM (B)

    // M[i][j] = (i>=j) ? E[i]*R[j]*CB : 0, overwrite sBM row-major
    #pragma unroll
    for (int tj = 0; tj < 4; ++tj) {
        #pragma unroll
        for (int r = 0; r < 4; ++r) {
            const int i = w * 16 + il + r;
            const int j = tj * 16 + (l & 15);
            const float v = (i >= j) ? sE[i] * sR[j] * accCB[tj][r] : 0.f;
            sBM[i * 64 + (j ^ ((i & 7) << 3))] = f2b(v);
        }
    }
    __syncthreads();   // M visible to all waves

    // mm2': Yt[p][i] = sum_j Xt[p][j] M[i][j];  mm4': It[p][i] = sum_s Ht[p][s] C[i][s]
    // wave w owns p in [16w,16w+16)
    f32x4 accY[4] = {zero, zero, zero, zero};
    f32x4 accI[4] = {zero, zero, zero, zero};
    #pragma unroll
    for (int kk = 0; kk < 2; ++kk) {
        const bf16x8 aX = frag_tr(sXt, w, kk, l);
        const bf16x8 aH = frag_rm(sH, w, kk, l);
        #pragma unroll
        for (int ti = 0; ti < 4; ++ti) {
            accY[ti] = __builtin_amdgcn_mfma_f32_16x16x32_bf16(aX, frag_rm(sBM, ti, kk, l), accY[ti], 0, 0, 0);
            accI[ti] = __builtin_amdgcn_mfma_f32_16x16x32_bf16(aH, frag_rm(sC, ti, kk, l), accI[ti], 0, 0, 0);
        }
    }

    // store: lane: i = ti*16 + (l&15), p = 16w + (l>>4)*4 + r (4 consecutive -> float4)
    const int pbase = w * 16 + il;
    #pragma unroll
    for (int ti = 0; ti < 4; ++ti) {
        const int i = ti * 16 + (l & 15);
        const float dfs = sE[i];
        float4 o;
        o.x = accY[ti][0] + dfs * accI[ti][0];
        o.y = accY[ti][1] + dfs * accI[ti][1];
        o.z = accY[ti][2] + dfs * accI[ti][2];
        o.w = accY[ti][3] + dfs * accI[ti][3];
        *(float4*)&Yg[((unsigned)(row0 + i) * NH + h) * 64 + pbase] = o;
    }
}

extern "C" void kernel_launch(void* const* d_in, const int* in_sizes, int n_in,
                              void* d_out, int out_size, void* d_ws, size_t ws_size,
                              hipStream_t stream) {
    const float* X = (const float*)d_in[0];
    const float* A = (const float*)d_in[1];
    const float* Bm = (const float*)d_in[2];
    const float* Cm = (const float*)d_in[3];
    float* Y = (float*)d_out;
    unsigned short* hws = (unsigned short*)d_ws;       // 16.8 MB bf16
    float* dws = (float*)(hws + HWS_ELEMS);            // per-chunk decays

    ssd_hfinal<<<BSZ * NH * NC, 256, 0, stream>>>(X, A, Bm, hws, dws);
    ssd_scan<<<BSZ * NH * SCAN_G, 256, 0, stream>>>(hws, dws);
    ssd_y<<<BSZ * NH * NC, 256, 0, stream>>>(X, A, Bm, Cm, hws, Y);
}